// Round 6
// baseline (489.241 us; speedup 1.0000x reference)
//
#include <hip/hip_runtime.h>
#include <math.h>

#define BB 4
#define CC 256
#define NHEAD 4
#define DH 32
#define NN 4096
#define HID 128

typedef _Float16 f16;
typedef _Float16 f16x8 __attribute__((ext_vector_type(8)));
typedef _Float16 f16x4 __attribute__((ext_vector_type(4)));
typedef float f32x4 __attribute__((ext_vector_type(4)));

// q-hat prescaled by 10*log2(e); softmax shift folded into MFMA C-init.
#define QPRESCALE 14.42695041f
#define NSHIFT 14.42695041f

#if __has_builtin(__builtin_amdgcn_exp2f)
#define EXP2F(x) __builtin_amdgcn_exp2f(x)
#else
#define EXP2F(x) __expf((x)*0.6931471805599453f)
#endif

// ---------------- kernel 0: weights -> f16 ----------------
__global__ __launch_bounds__(256) void cvt_w(const float* __restrict__ wq,
                                             const float* __restrict__ wo,
                                             f16* __restrict__ wq16,
                                             f16* __restrict__ wo16) {
    int t = blockIdx.x * 256 + threadIdx.x;
    if (t < 384 * 256) wq16[t] = (f16)wq[t];
    int u = t - 384 * 256;
    if (u >= 0 && u < 256 * 128) wo16[u] = (f16)wo[u];
}

// ---------------- kernel 1: x[b][c][i] fp32 -> xT[b][i][c] f16 ----------------
__global__ __launch_bounds__(256) void cvt_x(const float* __restrict__ x,
                                             f16* __restrict__ xT) {
    __shared__ float tile[64][65];
    int b = blockIdx.z;
    int i0 = blockIdx.x * 64, c0 = blockIdx.y * 64;
    int tx = threadIdx.x & 63, ty = threadIdx.x >> 6;  // ty 0..3
    const float* xb = x + (size_t)b * CC * NN;
#pragma unroll
    for (int cc = 0; cc < 16; cc++) {
        int c = cc * 4 + ty;
        tile[tx][c] = xb[(size_t)(c0 + c) * NN + i0 + tx];
    }
    __syncthreads();
    f16* xTb = xT + (size_t)b * NN * CC + (size_t)i0 * CC + c0;
    int il = threadIdx.x >> 3;  // 0..31
    int g = threadIdx.x & 7;
#pragma unroll
    for (int half = 0; half < 2; half++) {
        int i = il + half * 32;
        f16x8 v;
#pragma unroll
        for (int e = 0; e < 8; e++) v[e] = (f16)tile[i][g * 8 + e];
        *(f16x8*)(xTb + (size_t)i * CC + g * 8) = v;
    }
}

// ---------------- kernel 2: qkv GEMM (MFMA) ----------------
// out^T[i][o] = xT[i][c]·w^T[c][o]; wave tile 32 i x 64 o.
// q,k -> i-major f16 [bh][i][32] (unnormalized); v -> d-major f16 [bh][d][i].
__global__ __launch_bounds__(256) void qkv_mfma(const f16* __restrict__ xT,
                                                const f16* __restrict__ wq16,
                                                f16* __restrict__ qh,
                                                f16* __restrict__ kh,
                                                f16* __restrict__ vh) {
    int wave = threadIdx.x >> 6, lane = threadIdx.x & 63;
    int quad = lane >> 4, col = lane & 15;
    int b = blockIdx.z;
    int i0 = (blockIdx.x * 4 + wave) * 32;
    int o0 = blockIdx.y * 64;
    const f16* xb = xT + (size_t)b * NN * CC;

    const f32x4 z = {0.f, 0.f, 0.f, 0.f};
    f32x4 c[2][4];
#pragma unroll
    for (int it = 0; it < 2; it++)
#pragma unroll
        for (int ot = 0; ot < 4; ot++) c[it][ot] = z;

#pragma unroll
    for (int k0 = 0; k0 < CC; k0 += 32) {
        f16x8 a0 = *(const f16x8*)(xb + (size_t)(i0 + col) * CC + k0 + quad * 8);
        f16x8 a1 = *(const f16x8*)(xb + (size_t)(i0 + 16 + col) * CC + k0 + quad * 8);
#pragma unroll
        for (int ot = 0; ot < 4; ot++) {
            f16x8 bf = *(const f16x8*)(wq16 + (size_t)(o0 + ot * 16 + col) * CC + k0 + quad * 8);
            c[0][ot] = __builtin_amdgcn_mfma_f32_16x16x32_f16(a0, bf, c[0][ot], 0, 0, 0);
            c[1][ot] = __builtin_amdgcn_mfma_f32_16x16x32_f16(a1, bf, c[1][ot], 0, 0, 0);
        }
    }

#pragma unroll
    for (int it = 0; it < 2; it++)
#pragma unroll
        for (int ot = 0; ot < 4; ot++) {
            int o = o0 + ot * 16 + col;
            int i = i0 + it * 16 + quad * 4;
            if (o < 128) {
                int h = o >> 5, d = o & 31;
                f16* dst = qh + ((size_t)(b * 4 + h) * NN + i) * 32 + d;
#pragma unroll
                for (int r = 0; r < 4; r++) dst[(size_t)r * 32] = (f16)c[it][ot][r];
            } else if (o < 256) {
                int o2 = o - 128;
                int h = o2 >> 5, d = o2 & 31;
                f16* dst = kh + ((size_t)(b * 4 + h) * NN + i) * 32 + d;
#pragma unroll
                for (int r = 0; r < 4; r++) dst[(size_t)r * 32] = (f16)c[it][ot][r];
            } else {
                int o2 = o - 256;
                int h = o2 >> 5, d = o2 & 31;
                f16x4 v4;
#pragma unroll
                for (int r = 0; r < 4; r++) v4[r] = (f16)c[it][ot][r];
                *(f16x4*)(vh + ((size_t)(b * 4 + h) * 32 + d) * NN + i) = v4;
            }
        }
}

// ---------------- kernel 3: l2 normalize rows (i-major, in place) -------------
__global__ __launch_bounds__(256) void l2norm16(f16* __restrict__ qh,
                                                f16* __restrict__ kh) {
    size_t idx = (size_t)blockIdx.x * 256 + threadIdx.x;  // over bh*NN
    f16* p = (blockIdx.y == 0 ? qh : kh) + idx * 32;
    float extra = (blockIdx.y == 0) ? QPRESCALE : 1.0f;
    f16x8 v[4];
    float ss = 0.f;
#pragma unroll
    for (int g = 0; g < 4; g++) {
        v[g] = *(const f16x8*)(p + g * 8);
#pragma unroll
        for (int e = 0; e < 8; e++) {
            float f = (float)v[g][e];
            ss = fmaf(f, f, ss);
        }
    }
    float inv = extra / fmaxf(sqrtf(ss), 1e-12f);
#pragma unroll
    for (int g = 0; g < 4; g++) {
#pragma unroll
        for (int e = 0; e < 8; e++) v[g][e] = (f16)((float)v[g][e] * inv);
        *(f16x8*)(p + g * 8) = v[g];
    }
}

// ---------------- kernel 4: MFMA flash attention, 4-way key split -------------
struct KV32 {
    f16x8 k0, k1;
    f16x4 v0n0, v0n1, v1n0, v1n1;
};

__device__ __forceinline__ KV32 load_kv(const f16* __restrict__ kb,
                                        const f16* __restrict__ vb,
                                        int jb, int col, int quad) {
    KV32 f;
    f.k0 = *(const f16x8*)(kb + (size_t)(jb + col) * 32 + quad * 8);
    f.k1 = *(const f16x8*)(kb + (size_t)(jb + 16 + col) * 32 + quad * 8);
    f.v0n0 = *(const f16x4*)(vb + (size_t)col * NN + jb + quad * 4);
    f.v0n1 = *(const f16x4*)(vb + (size_t)(16 + col) * NN + jb + quad * 4);
    f.v1n0 = *(const f16x4*)(vb + (size_t)col * NN + jb + 16 + quad * 4);
    f.v1n1 = *(const f16x4*)(vb + (size_t)(16 + col) * NN + jb + 16 + quad * 4);
    return f;
}

__device__ __forceinline__ f16x4 expblk(f32x4 s, float& lacc) {
    float p0 = EXP2F(s[0]), p1 = EXP2F(s[1]);
    float p2 = EXP2F(s[2]), p3 = EXP2F(s[3]);
    lacc += (p0 + p1) + (p2 + p3);
    f16x4 r;
    r[0] = (f16)p0; r[1] = (f16)p1; r[2] = (f16)p2; r[3] = (f16)p3;
    return r;
}

__device__ __forceinline__ void compute32(const KV32& f, f16x8 qB0, f16x8 qB1,
                                          f32x4& o00, f32x4& o01,
                                          f32x4& o10, f32x4& o11,
                                          float& l0, float& l1) {
    const f32x4 zs = {-NSHIFT, -NSHIFT, -NSHIFT, -NSHIFT};  // shift folded into C
    f32x4 s00 = __builtin_amdgcn_mfma_f32_16x16x32_f16(f.k0, qB0, zs, 0, 0, 0);
    f32x4 s10 = __builtin_amdgcn_mfma_f32_16x16x32_f16(f.k0, qB1, zs, 0, 0, 0);
    f32x4 s01 = __builtin_amdgcn_mfma_f32_16x16x32_f16(f.k1, qB0, zs, 0, 0, 0);
    f32x4 s11 = __builtin_amdgcn_mfma_f32_16x16x32_f16(f.k1, qB1, zs, 0, 0, 0);
    f16x4 p00 = expblk(s00, l0);
    f16x4 p10 = expblk(s10, l1);
    f16x4 p01 = expblk(s01, l0);
    f16x4 p11 = expblk(s11, l1);
    o00 = __builtin_amdgcn_mfma_f32_16x16x16f16(p00, f.v0n0, o00, 0, 0, 0);
    o01 = __builtin_amdgcn_mfma_f32_16x16x16f16(p00, f.v0n1, o01, 0, 0, 0);
    o10 = __builtin_amdgcn_mfma_f32_16x16x16f16(p10, f.v0n0, o10, 0, 0, 0);
    o11 = __builtin_amdgcn_mfma_f32_16x16x16f16(p10, f.v0n1, o11, 0, 0, 0);
    o00 = __builtin_amdgcn_mfma_f32_16x16x16f16(p01, f.v1n0, o00, 0, 0, 0);
    o01 = __builtin_amdgcn_mfma_f32_16x16x16f16(p01, f.v1n1, o01, 0, 0, 0);
    o10 = __builtin_amdgcn_mfma_f32_16x16x16f16(p11, f.v1n0, o10, 0, 0, 0);
    o11 = __builtin_amdgcn_mfma_f32_16x16x16f16(p11, f.v1n1, o11, 0, 0, 0);
}

__global__ __launch_bounds__(256, 8) void attn_mfma(const f16* __restrict__ qh,
                                                    const f16* __restrict__ kh,
                                                    const f16* __restrict__ vh,
                                                    f16* __restrict__ att16) {
    __shared__ float olds[4][32][33];
    __shared__ float llds[4][32];
    int t = threadIdx.x;
    int wave = t >> 6, lane = t & 63;
    int quad = lane >> 4, col = lane & 15;
    int bh = blockIdx.y;
    int i0 = blockIdx.x * 32;

    const f16* qb = qh + (size_t)bh * NN * 32;
    const f16* kb = kh + (size_t)bh * NN * 32;
    const f16* vb = vh + (size_t)bh * 32 * NN;

    f16x8 qB0 = *(const f16x8*)(qb + (size_t)(i0 + col) * 32 + quad * 8);
    f16x8 qB1 = *(const f16x8*)(qb + (size_t)(i0 + 16 + col) * 32 + quad * 8);

    f32x4 o00 = {0.f, 0.f, 0.f, 0.f}, o01 = o00, o10 = o00, o11 = o00;
    float l0 = 0.f, l1 = 0.f;

    int jbeg = wave * 1024, jend = jbeg + 1024;
    KV32 c0 = load_kv(kb, vb, jbeg, col, quad);
    for (int j = jbeg; j < jend; j += 64) {
        KV32 c1 = load_kv(kb, vb, j + 32, col, quad);
        compute32(c0, qB0, qB1, o00, o01, o10, o11, l0, l1);
        if (j + 64 < jend) c0 = load_kv(kb, vb, j + 64, col, quad);
        compute32(c1, qB0, qB1, o00, o01, o10, o11, l0, l1);
    }

    // wave-local l reduction (keys split across quads)
    l0 += __shfl_xor(l0, 16); l0 += __shfl_xor(l0, 32);
    l1 += __shfl_xor(l1, 16); l1 += __shfl_xor(l1, 32);

#pragma unroll
    for (int r = 0; r < 4; r++) {
        olds[wave][quad * 4 + r][col]       = o00[r];
        olds[wave][quad * 4 + r][16 + col]  = o01[r];
        olds[wave][16 + quad * 4 + r][col]      = o10[r];
        olds[wave][16 + quad * 4 + r][16 + col] = o11[r];
    }
    if (quad == 0) {
        llds[wave][col] = l0;
        llds[wave][16 + col] = l1;
    }
    __syncthreads();

    // combine 4 key-chunks, normalize, store f16 i-major att16[b][i][h*32+dh]
    int ii = t >> 3;
    int g = t & 7;
    float sum[4];
#pragma unroll
    for (int e = 0; e < 4; e++)
        sum[e] = olds[0][ii][g * 4 + e] + olds[1][ii][g * 4 + e] +
                 olds[2][ii][g * 4 + e] + olds[3][ii][g * 4 + e];
    float l = llds[0][ii] + llds[1][ii] + llds[2][ii] + llds[3][ii];
    float inv = 1.0f / l;
    f16x4 o4;
#pragma unroll
    for (int e = 0; e < 4; e++) o4[e] = (f16)(sum[e] * inv);
    int b = bh >> 2, h = bh & 3;
    *(f16x4*)(att16 + ((size_t)b * NN + i0 + ii) * HID + h * 32 + g * 4) = o4;
}

// ---------------- kernel 5: output projection (MFMA) + bias ----------------
__global__ __launch_bounds__(256) void out_mfma(const f16* __restrict__ att16,
                                                const f16* __restrict__ wo16,
                                                const float* __restrict__ bo,
                                                float* __restrict__ out) {
    int wave = threadIdx.x >> 6, lane = threadIdx.x & 63;
    int quad = lane >> 4, col = lane & 15;
    int b = blockIdx.z;
    int i0 = (blockIdx.x * 4 + wave) * 32;
    int o0 = blockIdx.y * 64;
    const f16* ab = att16 + (size_t)b * NN * HID;

    const f32x4 z = {0.f, 0.f, 0.f, 0.f};
    f32x4 c[2][4];
#pragma unroll
    for (int it = 0; it < 2; it++)
#pragma unroll
        for (int ot = 0; ot < 4; ot++) c[it][ot] = z;

#pragma unroll
    for (int k0 = 0; k0 < HID; k0 += 32) {
        f16x8 a0 = *(const f16x8*)(ab + (size_t)(i0 + col) * HID + k0 + quad * 8);
        f16x8 a1 = *(const f16x8*)(ab + (size_t)(i0 + 16 + col) * HID + k0 + quad * 8);
#pragma unroll
        for (int ot = 0; ot < 4; ot++) {
            f16x8 bf = *(const f16x8*)(wo16 + (size_t)(o0 + ot * 16 + col) * HID + k0 + quad * 8);
            c[0][ot] = __builtin_amdgcn_mfma_f32_16x16x32_f16(a0, bf, c[0][ot], 0, 0, 0);
            c[1][ot] = __builtin_amdgcn_mfma_f32_16x16x32_f16(a1, bf, c[1][ot], 0, 0, 0);
        }
    }

#pragma unroll
    for (int it = 0; it < 2; it++)
#pragma unroll
        for (int ot = 0; ot < 4; ot++) {
            int o = o0 + ot * 16 + col;
            float bias = bo[o];
            int i = i0 + it * 16 + quad * 4;
            float4 st = {c[it][ot][0] + bias, c[it][ot][1] + bias,
                         c[it][ot][2] + bias, c[it][ot][3] + bias};
            *(float4*)(out + ((size_t)b * CC + o) * NN + i) = st;
        }
}

extern "C" void kernel_launch(void* const* d_in, const int* in_sizes, int n_in,
                              void* d_out, int out_size, void* d_ws, size_t ws_size,
                              hipStream_t stream) {
    const float* x     = (const float*)d_in[0];
    const float* w_qkv = (const float*)d_in[1];
    const float* w_out = (const float*)d_in[2];
    const float* b_out = (const float*)d_in[3];
    float* out = (float*)d_out;

    char* ws = (char*)d_ws;
    f16* qh    = (f16*)(ws);                        // 4 MB
    f16* kh    = (f16*)(ws + (4u << 20));           // 4 MB
    f16* vh    = (f16*)(ws + (8u << 20));           // 4 MB
    f16* att16 = (f16*)(ws + (12u << 20));          // 4 MB
    f16* xT    = (f16*)(ws + (16u << 20));          // 8 MB
    f16* wq16  = (f16*)(ws + (24u << 20));          // 192 KB
    f16* wo16  = (f16*)(ws + (24u << 20) + 262144); // 64 KB

    cvt_w<<<dim3(512), 256, 0, stream>>>(w_qkv, w_out, wq16, wo16);
    cvt_x<<<dim3(NN / 64, CC / 64, BB), 256, 0, stream>>>(x, xT);
    qkv_mfma<<<dim3(NN / 128, 384 / 64, BB), 256, 0, stream>>>(xT, wq16, qh, kh, vh);
    l2norm16<<<dim3(BB * NHEAD * NN / 256, 2), 256, 0, stream>>>(qh, kh);
    attn_mfma<<<dim3(NN / 32, BB * NHEAD), 256, 0, stream>>>(qh, kh, vh, att16);
    out_mfma<<<dim3(NN / 128, CC / 64, BB), 256, 0, stream>>>(att16, wo16, b_out, out);
}

// Round 7
// 217.167 us; speedup vs baseline: 2.2528x; 2.2528x over previous
//
#include <hip/hip_runtime.h>
#include <math.h>

#define BB 4
#define CC 256
#define NHEAD 4
#define DH 32
#define NN 4096
#define HID 128

typedef _Float16 f16;
typedef _Float16 f16x8 __attribute__((ext_vector_type(8)));
typedef _Float16 f16x4 __attribute__((ext_vector_type(4)));
typedef float f32x4 __attribute__((ext_vector_type(4)));

// q-hat prescaled by 10*log2(e); softmax shift folded into MFMA C-init.
#define QPRESCALE 14.42695041f
#define NSHIFT 14.42695041f

#if __has_builtin(__builtin_amdgcn_exp2f)
#define EXP2F(x) __builtin_amdgcn_exp2f(x)
#else
#define EXP2F(x) __expf((x)*0.6931471805599453f)
#endif

// ---------------- kernel 0: weights -> f16 ----------------
__global__ __launch_bounds__(256) void cvt_w(const float* __restrict__ wq,
                                             const float* __restrict__ wo,
                                             f16* __restrict__ wq16,
                                             f16* __restrict__ wo16) {
    int t = blockIdx.x * 256 + threadIdx.x;
    if (t < 384 * 256) wq16[t] = (f16)wq[t];
    int u = t - 384 * 256;
    if (u >= 0 && u < 256 * 128) wo16[u] = (f16)wo[u];
}

// ---------------- kernel 1: x[b][c][i] fp32 -> xT[b][i][c] f16 ----------------
__global__ __launch_bounds__(256) void cvt_x(const float* __restrict__ x,
                                             f16* __restrict__ xT) {
    __shared__ float tile[64][65];
    int b = blockIdx.z;
    int i0 = blockIdx.x * 64, c0 = blockIdx.y * 64;
    int tx = threadIdx.x & 63, ty = threadIdx.x >> 6;  // ty 0..3
    const float* xb = x + (size_t)b * CC * NN;
#pragma unroll
    for (int cc = 0; cc < 16; cc++) {
        int c = cc * 4 + ty;
        tile[tx][c] = xb[(size_t)(c0 + c) * NN + i0 + tx];
    }
    __syncthreads();
    f16* xTb = xT + (size_t)b * NN * CC + (size_t)i0 * CC + c0;
    int il = threadIdx.x >> 3;  // 0..31
    int g = threadIdx.x & 7;
#pragma unroll
    for (int half = 0; half < 2; half++) {
        int i = il + half * 32;
        f16x8 v;
#pragma unroll
        for (int e = 0; e < 8; e++) v[e] = (f16)tile[i][g * 8 + e];
        *(f16x8*)(xTb + (size_t)i * CC + g * 8) = v;
    }
}

// ---------------- kernel 2: qkv GEMM (MFMA) ----------------
__global__ __launch_bounds__(256) void qkv_mfma(const f16* __restrict__ xT,
                                                const f16* __restrict__ wq16,
                                                f16* __restrict__ qh,
                                                f16* __restrict__ kh,
                                                f16* __restrict__ vh) {
    int wave = threadIdx.x >> 6, lane = threadIdx.x & 63;
    int quad = lane >> 4, col = lane & 15;
    int b = blockIdx.z;
    int i0 = (blockIdx.x * 4 + wave) * 32;
    int o0 = blockIdx.y * 64;
    const f16* xb = xT + (size_t)b * NN * CC;

    const f32x4 z = {0.f, 0.f, 0.f, 0.f};
    f32x4 c[2][4];
#pragma unroll
    for (int it = 0; it < 2; it++)
#pragma unroll
        for (int ot = 0; ot < 4; ot++) c[it][ot] = z;

#pragma unroll
    for (int k0 = 0; k0 < CC; k0 += 32) {
        f16x8 a0 = *(const f16x8*)(xb + (size_t)(i0 + col) * CC + k0 + quad * 8);
        f16x8 a1 = *(const f16x8*)(xb + (size_t)(i0 + 16 + col) * CC + k0 + quad * 8);
#pragma unroll
        for (int ot = 0; ot < 4; ot++) {
            f16x8 bf = *(const f16x8*)(wq16 + (size_t)(o0 + ot * 16 + col) * CC + k0 + quad * 8);
            c[0][ot] = __builtin_amdgcn_mfma_f32_16x16x32_f16(a0, bf, c[0][ot], 0, 0, 0);
            c[1][ot] = __builtin_amdgcn_mfma_f32_16x16x32_f16(a1, bf, c[1][ot], 0, 0, 0);
        }
    }

#pragma unroll
    for (int it = 0; it < 2; it++)
#pragma unroll
        for (int ot = 0; ot < 4; ot++) {
            int o = o0 + ot * 16 + col;
            int i = i0 + it * 16 + quad * 4;
            if (o < 128) {
                int h = o >> 5, d = o & 31;
                f16* dst = qh + ((size_t)(b * 4 + h) * NN + i) * 32 + d;
#pragma unroll
                for (int r = 0; r < 4; r++) dst[(size_t)r * 32] = (f16)c[it][ot][r];
            } else if (o < 256) {
                int o2 = o - 128;
                int h = o2 >> 5, d = o2 & 31;
                f16* dst = kh + ((size_t)(b * 4 + h) * NN + i) * 32 + d;
#pragma unroll
                for (int r = 0; r < 4; r++) dst[(size_t)r * 32] = (f16)c[it][ot][r];
            } else {
                int o2 = o - 256;
                int h = o2 >> 5, d = o2 & 31;
                f16x4 v4;
#pragma unroll
                for (int r = 0; r < 4; r++) v4[r] = (f16)c[it][ot][r];
                *(f16x4*)(vh + ((size_t)(b * 4 + h) * 32 + d) * NN + i) = v4;
            }
        }
}

// ---------------- kernel 3: l2 normalize rows (i-major, in place) -------------
__global__ __launch_bounds__(256) void l2norm16(f16* __restrict__ qh,
                                                f16* __restrict__ kh) {
    size_t idx = (size_t)blockIdx.x * 256 + threadIdx.x;  // over bh*NN
    f16* p = (blockIdx.y == 0 ? qh : kh) + idx * 32;
    float extra = (blockIdx.y == 0) ? QPRESCALE : 1.0f;
    f16x8 v[4];
    float ss = 0.f;
#pragma unroll
    for (int g = 0; g < 4; g++) {
        v[g] = *(const f16x8*)(p + g * 8);
#pragma unroll
        for (int e = 0; e < 8; e++) {
            float f = (float)v[g][e];
            ss = fmaf(f, f, ss);
        }
    }
    float inv = extra / fmaxf(sqrtf(ss), 1e-12f);
#pragma unroll
    for (int g = 0; g < 4; g++) {
#pragma unroll
        for (int e = 0; e < 8; e++) v[g][e] = (f16)((float)v[g][e] * inv);
        *(f16x8*)(p + g * 8) = v[g];
    }
}

// ---------------- kernel 4: MFMA flash attention ----------------
// 64 q-rows per block (4 q-tiles of 16), 4-way key split across waves,
// XCD-aware bh grouping: all blocks of a given bh land on one XCD so its
// 1 MB K/V stays resident in that XCD's 4 MB L2.
struct KV32 {
    f16x8 k0, k1;
    f16x4 v0n0, v0n1, v1n0, v1n1;
};

__device__ __forceinline__ KV32 load_kv(const f16* __restrict__ kb,
                                        const f16* __restrict__ vb,
                                        int jb, int col, int quad) {
    KV32 f;
    f.k0 = *(const f16x8*)(kb + (size_t)(jb + col) * 32 + quad * 8);
    f.k1 = *(const f16x8*)(kb + (size_t)(jb + 16 + col) * 32 + quad * 8);
    f.v0n0 = *(const f16x4*)(vb + (size_t)col * NN + jb + quad * 4);
    f.v0n1 = *(const f16x4*)(vb + (size_t)(16 + col) * NN + jb + quad * 4);
    f.v1n0 = *(const f16x4*)(vb + (size_t)col * NN + jb + 16 + quad * 4);
    f.v1n1 = *(const f16x4*)(vb + (size_t)(16 + col) * NN + jb + 16 + quad * 4);
    return f;
}

__device__ __forceinline__ f16x4 expblk(f32x4 s, float& lacc) {
    float p0 = EXP2F(s[0]), p1 = EXP2F(s[1]);
    float p2 = EXP2F(s[2]), p3 = EXP2F(s[3]);
    lacc += (p0 + p1) + (p2 + p3);
    f16x4 r;
    r[0] = (f16)p0; r[1] = (f16)p1; r[2] = (f16)p2; r[3] = (f16)p3;
    return r;
}

__device__ __forceinline__ void compute32(const KV32& f, const f16x8* qB,
                                          f32x4 (*o)[2], float* l) {
    const f32x4 zs = {-NSHIFT, -NSHIFT, -NSHIFT, -NSHIFT};
#pragma unroll
    for (int qt = 0; qt < 4; qt++) {
        f32x4 s0 = __builtin_amdgcn_mfma_f32_16x16x32_f16(f.k0, qB[qt], zs, 0, 0, 0);
        f32x4 s1 = __builtin_amdgcn_mfma_f32_16x16x32_f16(f.k1, qB[qt], zs, 0, 0, 0);
        f16x4 p0 = expblk(s0, l[qt]);
        f16x4 p1 = expblk(s1, l[qt]);
        o[qt][0] = __builtin_amdgcn_mfma_f32_16x16x16f16(p0, f.v0n0, o[qt][0], 0, 0, 0);
        o[qt][1] = __builtin_amdgcn_mfma_f32_16x16x16f16(p0, f.v0n1, o[qt][1], 0, 0, 0);
        o[qt][0] = __builtin_amdgcn_mfma_f32_16x16x16f16(p1, f.v1n0, o[qt][0], 0, 0, 0);
        o[qt][1] = __builtin_amdgcn_mfma_f32_16x16x16f16(p1, f.v1n1, o[qt][1], 0, 0, 0);
    }
}

__global__ __launch_bounds__(256, 4) void attn_mfma(const f16* __restrict__ qh,
                                                    const f16* __restrict__ kh,
                                                    const f16* __restrict__ vh,
                                                    f16* __restrict__ att16) {
    __shared__ float olds[4][64][33];  // [wave][q-row][dh]
    __shared__ float llds[4][64];
    int t = threadIdx.x;
    int wave = t >> 6, lane = t & 63;
    int quad = lane >> 4, col = lane & 15;

    // XCD-aware decomposition: 1024 blocks, bid%8 -> XCD (dispatch heuristic);
    // each XCD owns 2 bh. Correctness independent of the mapping.
    int bid = blockIdx.x;
    int xcd = bid & 7;
    int slot = bid >> 3;             // 0..127
    int bh = xcd * 2 + (slot >> 6);  // 0..15
    int i0 = (slot & 63) * 64;

    const f16* qb = qh + (size_t)bh * NN * 32;
    const f16* kb = kh + (size_t)bh * NN * 32;
    const f16* vb = vh + (size_t)bh * 32 * NN;

    f16x8 qB[4];
#pragma unroll
    for (int qt = 0; qt < 4; qt++)
        qB[qt] = *(const f16x8*)(qb + (size_t)(i0 + qt * 16 + col) * 32 + quad * 8);

    f32x4 o[4][2];
    float l[4];
#pragma unroll
    for (int qt = 0; qt < 4; qt++) {
        o[qt][0] = f32x4{0.f, 0.f, 0.f, 0.f};
        o[qt][1] = f32x4{0.f, 0.f, 0.f, 0.f};
        l[qt] = 0.f;
    }

    int jbeg = wave * 1024, jend = jbeg + 1024;
    KV32 c0 = load_kv(kb, vb, jbeg, col, quad);
    for (int j = jbeg; j < jend; j += 64) {
        KV32 c1 = load_kv(kb, vb, j + 32, col, quad);
        compute32(c0, qB, o, l);
        if (j + 64 < jend) c0 = load_kv(kb, vb, j + 64, col, quad);
        compute32(c1, qB, o, l);
    }

    // reduce l across quads (wave-local), stash everything in LDS
#pragma unroll
    for (int qt = 0; qt < 4; qt++) {
        l[qt] += __shfl_xor(l[qt], 16);
        l[qt] += __shfl_xor(l[qt], 32);
#pragma unroll
        for (int r = 0; r < 4; r++) {
            olds[wave][qt * 16 + quad * 4 + r][col] = o[qt][0][r];
            olds[wave][qt * 16 + quad * 4 + r][16 + col] = o[qt][1][r];
        }
        if (quad == 0) llds[wave][qt * 16 + col] = l[qt];
    }
    __syncthreads();

    // combine 4 key-chunks, normalize, store f16 i-major att16[b][i][h*32+dh]
    int ii = t >> 2;   // 0..63
    int g = t & 3;     // 8 dh each
    float sum[8];
#pragma unroll
    for (int e = 0; e < 8; e++)
        sum[e] = olds[0][ii][g * 8 + e] + olds[1][ii][g * 8 + e] +
                 olds[2][ii][g * 8 + e] + olds[3][ii][g * 8 + e];
    float lt = llds[0][ii] + llds[1][ii] + llds[2][ii] + llds[3][ii];
    float inv = 1.0f / lt;
    f16x8 o8;
#pragma unroll
    for (int e = 0; e < 8; e++) o8[e] = (f16)(sum[e] * inv);
    int b = bh >> 2, h = bh & 3;
    *(f16x8*)(att16 + ((size_t)b * NN + i0 + ii) * HID + h * 32 + g * 8) = o8;
}

// ---------------- kernel 5: output projection (MFMA) + bias ----------------
__global__ __launch_bounds__(256) void out_mfma(const f16* __restrict__ att16,
                                                const f16* __restrict__ wo16,
                                                const float* __restrict__ bo,
                                                float* __restrict__ out) {
    int wave = threadIdx.x >> 6, lane = threadIdx.x & 63;
    int quad = lane >> 4, col = lane & 15;
    int b = blockIdx.z;
    int i0 = (blockIdx.x * 4 + wave) * 32;
    int o0 = blockIdx.y * 64;
    const f16* ab = att16 + (size_t)b * NN * HID;

    const f32x4 z = {0.f, 0.f, 0.f, 0.f};
    f32x4 c[2][4];
#pragma unroll
    for (int it = 0; it < 2; it++)
#pragma unroll
        for (int ot = 0; ot < 4; ot++) c[it][ot] = z;

#pragma unroll
    for (int k0 = 0; k0 < HID; k0 += 32) {
        f16x8 a0 = *(const f16x8*)(ab + (size_t)(i0 + col) * HID + k0 + quad * 8);
        f16x8 a1 = *(const f16x8*)(ab + (size_t)(i0 + 16 + col) * HID + k0 + quad * 8);
#pragma unroll
        for (int ot = 0; ot < 4; ot++) {
            f16x8 bf = *(const f16x8*)(wo16 + (size_t)(o0 + ot * 16 + col) * HID + k0 + quad * 8);
            c[0][ot] = __builtin_amdgcn_mfma_f32_16x16x32_f16(a0, bf, c[0][ot], 0, 0, 0);
            c[1][ot] = __builtin_amdgcn_mfma_f32_16x16x32_f16(a1, bf, c[1][ot], 0, 0, 0);
        }
    }

#pragma unroll
    for (int it = 0; it < 2; it++)
#pragma unroll
        for (int ot = 0; ot < 4; ot++) {
            int o = o0 + ot * 16 + col;
            float bias = bo[o];
            int i = i0 + it * 16 + quad * 4;
            float4 st = {c[it][ot][0] + bias, c[it][ot][1] + bias,
                         c[it][ot][2] + bias, c[it][ot][3] + bias};
            *(float4*)(out + ((size_t)b * CC + o) * NN + i) = st;
        }
}

extern "C" void kernel_launch(void* const* d_in, const int* in_sizes, int n_in,
                              void* d_out, int out_size, void* d_ws, size_t ws_size,
                              hipStream_t stream) {
    const float* x     = (const float*)d_in[0];
    const float* w_qkv = (const float*)d_in[1];
    const float* w_out = (const float*)d_in[2];
    const float* b_out = (const float*)d_in[3];
    float* out = (float*)d_out;

    char* ws = (char*)d_ws;
    f16* qh    = (f16*)(ws);                        // 4 MB
    f16* kh    = (f16*)(ws + (4u << 20));           // 4 MB
    f16* vh    = (f16*)(ws + (8u << 20));           // 4 MB
    f16* att16 = (f16*)(ws + (12u << 20));          // 4 MB
    f16* xT    = (f16*)(ws + (16u << 20));          // 8 MB
    f16* wq16  = (f16*)(ws + (24u << 20));          // 192 KB
    f16* wo16  = (f16*)(ws + (24u << 20) + 262144); // 64 KB

    cvt_w<<<dim3(512), 256, 0, stream>>>(w_qkv, w_out, wq16, wo16);
    cvt_x<<<dim3(NN / 64, CC / 64, BB), 256, 0, stream>>>(x, xT);
    qkv_mfma<<<dim3(NN / 128, 384 / 64, BB), 256, 0, stream>>>(xT, wq16, qh, kh, vh);
    l2norm16<<<dim3(BB * NHEAD * NN / 256, 2), 256, 0, stream>>>(qh, kh);
    attn_mfma<<<dim3(1024), 256, 0, stream>>>(qh, kh, vh, att16);
    out_mfma<<<dim3(NN / 128, CC / 64, BB), 256, 0, stream>>>(att16, wo16, b_out, out);
}